// Round 1
// baseline (16809.706 us; speedup 1.0000x reference)
//
#include <hip/hip_runtime.h>
#include <stdint.h>

// ---------------------------------------------------------------------------
// CustomGRU: B=64, S=512, I=256, H=1024
//  xg = x @ (Wi@Wgx) + (bi@Wgx + bg)   (one fused GEMM, 3 gates concat, N=3072)
//  scan: z = sig(xz + h@Wzh); r = sig(xr + h@Wrh);
//        n = tanh(xn + (r*h)@Wnh);  h' = (1-z)n + z h      [(r*h)@W per py prec]
// ---------------------------------------------------------------------------

using f32x4  = __attribute__((ext_vector_type(4))) float;
using bf16x8 = __attribute__((ext_vector_type(8))) __bf16;
using u16x8  = __attribute__((ext_vector_type(8))) unsigned short;
using u16x4  = __attribute__((ext_vector_type(4))) unsigned short;

__device__ __forceinline__ unsigned short f2bf(float x) {
  union { float f; uint32_t u; } v; v.f = x;
  uint32_t u = v.u;
  return (unsigned short)((u + 0x7fffu + ((u >> 16) & 1u)) >> 16);  // RNE
}
__device__ __forceinline__ float bf2f(unsigned short u) {
  union { uint32_t u; float f; } v; v.u = ((uint32_t)u) << 16;
  return v.f;
}
__device__ __forceinline__ bf16x8 ld_b8(const unsigned short* p) {
  return *(const bf16x8*)p;
}
__device__ __forceinline__ float xg_get(const float* p) { return *p; }
__device__ __forceinline__ float xg_get(const unsigned short* p) { return bf2f(*p); }
__device__ __forceinline__ void  xg_put(float* p, float v) { *p = v; }
__device__ __forceinline__ void  xg_put(unsigned short* p, float v) { *p = f2bf(v); }
__device__ __forceinline__ float sigm(float x) { return 1.f / (1.f + __expf(-x)); }
__device__ __forceinline__ float tanh_(float x) { float e = __expf(2.f * x); return 1.f - 2.f / (e + 1.f); }

// ---------------------------------------------------------------------------
// K1: WcT[n(3072)][i(256)] (bf16) = (Wi @ Wgx)^T.  1.6 GFLOP.
// ---------------------------------------------------------------------------
__global__ __launch_bounds__(256) void wc_kernel(
    const float* __restrict__ Wi, const float* __restrict__ Wz,
    const float* __restrict__ Wr, const float* __restrict__ Wn,
    unsigned short* __restrict__ WcT)
{
  const int ntile = blockIdx.x >> 4, itile = blockIdx.x & 15;  // 48 x 16
  const int n_g = ntile * 64 + (threadIdx.x & 63);             // 0..3071
  const int g = n_g >> 10, n = n_g & 1023;
  const float* Wg = (g == 0) ? Wz : (g == 1) ? Wr : Wn;        // rows [0,H) = W*_x
  const int i0 = itile * 16 + ((threadIdx.x >> 6) << 2);
  float a0 = 0.f, a1 = 0.f, a2 = 0.f, a3 = 0.f;
  for (int k = 0; k < 1024; ++k) {
    const float wv = Wg[(size_t)k * 1024 + n];
    a0 += Wi[(i0 + 0) * 1024 + k] * wv;
    a1 += Wi[(i0 + 1) * 1024 + k] * wv;
    a2 += Wi[(i0 + 2) * 1024 + k] * wv;
    a3 += Wi[(i0 + 3) * 1024 + k] * wv;
  }
  WcT[(size_t)n_g * 256 + i0 + 0] = f2bf(a0);
  WcT[(size_t)n_g * 256 + i0 + 1] = f2bf(a1);
  WcT[(size_t)n_g * 256 + i0 + 2] = f2bf(a2);
  WcT[(size_t)n_g * 256 + i0 + 3] = f2bf(a3);
}

// ---------------------------------------------------------------------------
// K2: bc[n(3072)] = bi @ Wgx + bg  (fp32)
// ---------------------------------------------------------------------------
__global__ __launch_bounds__(256) void bc_kernel(
    const float* __restrict__ bi, const float* __restrict__ Wz,
    const float* __restrict__ Wr, const float* __restrict__ Wn,
    const float* __restrict__ bz, const float* __restrict__ br,
    const float* __restrict__ bn, float* __restrict__ bc)
{
  const int n_g = blockIdx.x * 256 + threadIdx.x;
  const int g = n_g >> 10, n = n_g & 1023;
  const float* Wg = (g == 0) ? Wz : (g == 1) ? Wr : Wn;
  const float* bg = (g == 0) ? bz : (g == 1) ? br : bn;
  float acc = bg[n];
  for (int k = 0; k < 1024; ++k) acc += bi[k] * Wg[(size_t)k * 1024 + n];
  bc[n_g] = acc;
}

// ---------------------------------------------------------------------------
// K3: WhhT[g][col(1024)][k(1024)] (bf16) = Wg[H + k][col]  (tile transpose)
// ---------------------------------------------------------------------------
__global__ __launch_bounds__(256) void whT_kernel(
    const float* __restrict__ Wz, const float* __restrict__ Wr,
    const float* __restrict__ Wn, unsigned short* __restrict__ WhhT)
{
  __shared__ float tile[64][65];
  const int g = blockIdx.x >> 8;
  const int rem = blockIdx.x & 255;
  const int kt = rem >> 4, ct = rem & 15;
  const float* Wg = (g == 0) ? Wz : (g == 1) ? Wr : Wn;
  const int tx = threadIdx.x & 63, ty = threadIdx.x >> 6;
  #pragma unroll
  for (int j = 0; j < 16; ++j) {
    const int k = kt * 64 + ty + j * 4;
    tile[ty + j * 4][tx] = Wg[(size_t)(1024 + k) * 1024 + ct * 64 + tx];
  }
  __syncthreads();
  #pragma unroll
  for (int j = 0; j < 16; ++j) {
    const int c = ct * 64 + ty + j * 4;
    WhhT[((size_t)g * 1024 + c) * 1024 + kt * 64 + tx] = f2bf(tile[tx][ty + j * 4]);
  }
}

// ---------------------------------------------------------------------------
// K4: gates GEMM  xg[s][b][3072] = x @ Wc + bc.  M=32768, N=3072, K=256.
// 128x128 tile, BK=64, 4 waves (2x2), bf16 MFMA 16x16x32, fp32 out.
// ---------------------------------------------------------------------------
template <typename XT>
__global__ __launch_bounds__(256) void gates_kernel(
    const float* __restrict__ x, const unsigned short* __restrict__ WcT,
    const float* __restrict__ bc, XT* __restrict__ xg)
{
  __shared__ __align__(16) unsigned short As[128 * 72];
  __shared__ __align__(16) unsigned short Bs[128 * 72];
  const int t = threadIdx.x;
  const int lane = t & 63, wid = t >> 6;
  const int wm = wid >> 1, wn = wid & 1;
  const int ml = lane & 15, quad = lane >> 4;
  const int mb = blockIdx.x / 24, nb = blockIdx.x % 24;
  const int m0 = mb * 128, n0 = nb * 128;
  f32x4 acc[4][4];
  #pragma unroll
  for (int i = 0; i < 4; ++i)
    #pragma unroll
    for (int j = 0; j < 4; ++j) acc[i][j] = (f32x4){0.f, 0.f, 0.f, 0.f};

  for (int kc = 0; kc < 4; ++kc) {
    {
      const int row = t >> 4, c4 = t & 15;
      #pragma unroll
      for (int i = 0; i < 8; ++i) {
        const f32x4 v = *(const f32x4*)(x + (size_t)(m0 + row + i * 16) * 256 + kc * 64 + c4 * 4);
        u16x4 b4 = { f2bf(v[0]), f2bf(v[1]), f2bf(v[2]), f2bf(v[3]) };
        *(u16x4*)&As[(row + i * 16) * 72 + c4 * 4] = b4;
      }
      const int rowB = t >> 3, ch = t & 7;
      #pragma unroll
      for (int i = 0; i < 4; ++i) {
        const u16x8 v = *(const u16x8*)(WcT + (size_t)(n0 + rowB + i * 32) * 256 + kc * 64 + ch * 8);
        *(u16x8*)&Bs[(rowB + i * 32) * 72 + ch * 8] = v;
      }
    }
    __syncthreads();
    #pragma unroll
    for (int kt = 0; kt < 2; ++kt) {
      bf16x8 a[4], b[4];
      #pragma unroll
      for (int mt = 0; mt < 4; ++mt) a[mt] = ld_b8(&As[(wm * 64 + mt * 16 + ml) * 72 + kt * 32 + quad * 8]);
      #pragma unroll
      for (int nt = 0; nt < 4; ++nt) b[nt] = ld_b8(&Bs[(wn * 64 + nt * 16 + ml) * 72 + kt * 32 + quad * 8]);
      #pragma unroll
      for (int mt = 0; mt < 4; ++mt)
        #pragma unroll
        for (int nt = 0; nt < 4; ++nt)
          acc[mt][nt] = __builtin_amdgcn_mfma_f32_16x16x32_bf16(a[mt], b[nt], acc[mt][nt], 0, 0, 0);
    }
    __syncthreads();
  }
  #pragma unroll
  for (int nt = 0; nt < 4; ++nt) {
    const int n = n0 + wn * 64 + nt * 16 + ml;
    const float bcv = bc[n];
    #pragma unroll
    for (int mt = 0; mt < 4; ++mt) {
      #pragma unroll
      for (int r = 0; r < 4; ++r) {
        const int m = m0 + wm * 64 + mt * 16 + quad * 4 + r;
        const int b = m >> 9, s = m & 511;
        xg_put(&xg[((size_t)s * 64 + b) * 3072 + n], acc[mt][nt][r] + bcv);
      }
    }
  }
}

// ---------------------------------------------------------------------------
// K5: persistent recurrence. 256 WGs = 4 batch-groups(16 b) x 64 col-groups(16 h).
// Weights LDS-resident frag-linear; peer sync via device-scope flags (2/step).
// ---------------------------------------------------------------------------
__device__ __forceinline__ void wait_peers(int* dom, int target) {
  const int lane = threadIdx.x & 63;
  int* fp = dom + lane * 32;
  while (true) {
    const int v = __hip_atomic_load(fp, __ATOMIC_RELAXED, __HIP_MEMORY_SCOPE_AGENT);
    if (__all(v >= target)) break;
    __builtin_amdgcn_s_sleep(1);
  }
}

template <typename XT>
__global__ __launch_bounds__(256, 1) void recur_kernel(
    const unsigned short* __restrict__ WhhT, const XT* __restrict__ xg,
    unsigned short* __restrict__ hbuf, unsigned short* __restrict__ rhbuf,
    int* __restrict__ flags, float* __restrict__ out, float* __restrict__ hfin)
{
  // LDS: 98304 + 33024 + 8192 + 1024 + 1024 = 141568 B  (1 WG/CU)
  __shared__ __align__(16) unsigned short w_lds[3 * 32 * 64 * 8];  // frag-linear [g][kt][lane][8]
  __shared__ __align__(16) unsigned short h_lds[16 * 1032];        // [b][k] padded +8
  __shared__ __align__(16) float red[8 * 64 * 4];
  __shared__ float zbuf[256];
  __shared__ float hprev[256];  // exact fp32 h for this WG's (b, col) slice

  const int tid = threadIdx.x;
  const int lane = tid & 63;
  const int wid = tid >> 6;
  const int ml = lane & 15;
  const int quad = lane >> 4;
  const int wg = blockIdx.x;
  const int bg = wg >> 6;   // batch group 0..3
  const int ng = wg & 63;   // col group 0..63

  // one-time weight staging: 6144 16B chunks
  for (int i = 0; i < 24; ++i) {
    const int c = tid + i * 256;
    const int l2 = c & 63;
    const int gkt = c >> 6;            // 0..95
    const int g = gkt >> 5, kt = gkt & 31;
    const int nl = l2 & 15, q2 = l2 >> 4;
    const u16x8 v = *(const u16x8*)(WhhT + ((size_t)g << 20) + (size_t)(ng * 16 + nl) * 1024 + kt * 32 + q2 * 8);
    *(u16x8*)&w_lds[(size_t)c * 8] = v;
  }
  hprev[tid] = 0.f;
  int* myflag = flags + wg * 32;
  int* dom = flags + (bg << 6) * 32;
  const int hrow = tid >> 4, hck = tid & 15;
  __syncthreads();

  for (int t = 0; t < 512; ++t) {
    // ================= phase A: z, r =================
    {
      const unsigned short* hb = hbuf + (size_t)(t & 1) * 65536 + (size_t)bg * 16 * 1024;
      #pragma unroll
      for (int i = 0; i < 8; ++i) {
        const u16x8 v = *(const u16x8*)(hb + (size_t)hrow * 1024 + hck * 8 + i * 128);
        *(u16x8*)&h_lds[hrow * 1032 + hck * 8 + i * 128] = v;
      }
    }
    float xgv[4];
    if (wid < 2) {
      const XT* xp = xg + ((size_t)t * 64 + bg * 16 + quad * 4) * 3072 + wid * 1024 + ng * 16 + ml;
      #pragma unroll
      for (int r = 0; r < 4; ++r) xgv[r] = xg_get(xp + (size_t)r * 3072);
    }
    __syncthreads();

    f32x4 accZ = {0.f, 0.f, 0.f, 0.f}, accR = {0.f, 0.f, 0.f, 0.f};
    {
      const unsigned short* arow = &h_lds[ml * 1032];
      #pragma unroll
      for (int k = 0; k < 8; ++k) {
        const int kt = wid * 8 + k;
        const bf16x8 av = ld_b8(arow + kt * 32 + quad * 8);
        const bf16x8 wz = ld_b8(&w_lds[((0 * 32 + kt) * 64 + lane) * 8]);
        const bf16x8 wr = ld_b8(&w_lds[((32 + kt) * 64 + lane) * 8]);
        accZ = __builtin_amdgcn_mfma_f32_16x16x32_bf16(av, wz, accZ, 0, 0, 0);
        accR = __builtin_amdgcn_mfma_f32_16x16x32_bf16(av, wr, accR, 0, 0, 0);
      }
    }
    *(f32x4*)&red[(wid * 2 + 0) * 256 + lane * 4] = accZ;
    *(f32x4*)&red[(wid * 2 + 1) * 256 + lane * 4] = accR;
    __syncthreads();

    if (wid == 0) {
      f32x4 s = {0.f, 0.f, 0.f, 0.f};
      #pragma unroll
      for (int w = 0; w < 4; ++w) s += *(const f32x4*)&red[(w * 2) * 256 + lane * 4];
      #pragma unroll
      for (int r = 0; r < 4; ++r) zbuf[(quad * 4 + r) * 16 + ml] = sigm(s[r] + xgv[r]);
    } else if (wid == 1) {
      f32x4 s = {0.f, 0.f, 0.f, 0.f};
      #pragma unroll
      for (int w = 0; w < 4; ++w) s += *(const f32x4*)&red[(w * 2 + 1) * 256 + lane * 4];
      #pragma unroll
      for (int r = 0; r < 4; ++r) {
        const float rr = sigm(s[r] + xgv[r]);
        const float hv = hprev[(quad * 4 + r) * 16 + ml];
        rhbuf[(size_t)(bg * 16 + quad * 4 + r) * 1024 + ng * 16 + ml] = f2bf(rr * hv);
      }
    }
    __syncthreads();
    if (tid == 0) { __threadfence(); atomicExch(myflag, 2 * t + 1); }
    if (wid == 0) { wait_peers(dom, 2 * t + 1); __threadfence(); }
    __syncthreads();

    // ================= phase B: n, h' =================
    {
      const unsigned short* rb = rhbuf + (size_t)bg * 16 * 1024;
      #pragma unroll
      for (int i = 0; i < 8; ++i) {
        const u16x8 v = *(const u16x8*)(rb + (size_t)hrow * 1024 + hck * 8 + i * 128);
        *(u16x8*)&h_lds[hrow * 1032 + hck * 8 + i * 128] = v;
      }
    }
    float xgn[4];
    if (wid == 0) {
      const XT* xp = xg + ((size_t)t * 64 + bg * 16 + quad * 4) * 3072 + 2048 + ng * 16 + ml;
      #pragma unroll
      for (int r = 0; r < 4; ++r) xgn[r] = xg_get(xp + (size_t)r * 3072);
    }
    __syncthreads();

    f32x4 accN = {0.f, 0.f, 0.f, 0.f};
    {
      const unsigned short* arow = &h_lds[ml * 1032];
      #pragma unroll
      for (int k = 0; k < 8; ++k) {
        const int kt = wid * 8 + k;
        const bf16x8 av = ld_b8(arow + kt * 32 + quad * 8);
        const bf16x8 wn = ld_b8(&w_lds[((64 + kt) * 64 + lane) * 8]);
        accN = __builtin_amdgcn_mfma_f32_16x16x32_bf16(av, wn, accN, 0, 0, 0);
      }
    }
    *(f32x4*)&red[wid * 256 + lane * 4] = accN;
    __syncthreads();
    if (wid == 0) {
      f32x4 s = {0.f, 0.f, 0.f, 0.f};
      #pragma unroll
      for (int w = 0; w < 4; ++w) s += *(const f32x4*)&red[w * 256 + lane * 4];
      #pragma unroll
      for (int r = 0; r < 4; ++r) {
        const int bl = quad * 4 + r;
        const float nv = tanh_(s[r] + xgn[r]);
        const float z = zbuf[bl * 16 + ml];
        const float hv = hprev[bl * 16 + ml];
        const float hn = (1.f - z) * nv + z * hv;
        hprev[bl * 16 + ml] = hn;
        const int b = bg * 16 + bl;
        out[((size_t)b * 512 + t) * 1024 + ng * 16 + ml] = hn;
        hbuf[(size_t)((t + 1) & 1) * 65536 + (size_t)b * 1024 + ng * 16 + ml] = f2bf(hn);
        if (t == 511) hfin[(size_t)b * 1024 + ng * 16 + ml] = hn;
      }
    }
    __syncthreads();
    if (tid == 0) { __threadfence(); atomicExch(myflag, 2 * t + 2); }
    if (wid == 0) { wait_peers(dom, 2 * t + 2); __threadfence(); }
    __syncthreads();
  }
}

// ---------------------------------------------------------------------------
extern "C" void kernel_launch(void* const* d_in, const int* in_sizes, int n_in,
                              void* d_out, int out_size, void* d_ws, size_t ws_size,
                              hipStream_t stream)
{
  const float* x  = (const float*)d_in[0];
  const float* Wi = (const float*)d_in[1];
  const float* bi = (const float*)d_in[2];
  const float* Wz = (const float*)d_in[3];
  const float* bz = (const float*)d_in[4];
  const float* Wr = (const float*)d_in[5];
  const float* br = (const float*)d_in[6];
  const float* Wn = (const float*)d_in[7];
  const float* bn = (const float*)d_in[8];
  float* out  = (float*)d_out;
  float* hfin = out + (size_t)64 * 512 * 1024;

  char* ws = (char*)d_ws;
  size_t off = 0;
  auto take = [&](size_t b) { size_t o = off; off += (b + 255) & ~(size_t)255; return o; };
  unsigned short* WhhT = (unsigned short*)(ws + take((size_t)3 * 1024 * 1024 * 2));
  unsigned short* WcT  = (unsigned short*)(ws + take((size_t)3072 * 256 * 2));
  float*          bc   = (float*)(ws + take(3072 * 4));
  unsigned short* hbuf = (unsigned short*)(ws + take((size_t)2 * 64 * 1024 * 2));
  unsigned short* rhb  = (unsigned short*)(ws + take((size_t)64 * 1024 * 2));
  int*            flags = (int*)(ws + take(256 * 32 * 4));
  const size_t xg_off = off;
  const bool xg_f32 = (ws_size >= xg_off + (size_t)32768 * 3072 * 4);
  void* xg = (void*)(ws + xg_off);

  hipMemsetAsync(hbuf, 0, (size_t)2 * 64 * 1024 * 2, stream);
  hipMemsetAsync(flags, 0, 256 * 32 * 4, stream);

  wc_kernel<<<768, 256, 0, stream>>>(Wi, Wz, Wr, Wn, WcT);
  bc_kernel<<<12, 256, 0, stream>>>(bi, Wz, Wr, Wn, bz, br, bn, bc);
  whT_kernel<<<768, 256, 0, stream>>>(Wz, Wr, Wn, WhhT);

  if (xg_f32) {
    gates_kernel<float><<<6144, 256, 0, stream>>>(x, WcT, bc, (float*)xg);
    const unsigned short* a0 = WhhT; const float* a1 = (const float*)xg;
    unsigned short* a2 = hbuf; unsigned short* a3 = rhb; int* a4 = flags;
    float* a5 = out; float* a6 = hfin;
    void* kargs[] = {&a0, &a1, &a2, &a3, &a4, &a5, &a6};
    hipError_t e = hipLaunchCooperativeKernel(
        reinterpret_cast<const void*>(&recur_kernel<float>),
        dim3(256), dim3(256), kargs, 0, stream);
    if (e != hipSuccess)
      recur_kernel<float><<<256, 256, 0, stream>>>(WhhT, (const float*)xg, hbuf, rhb, flags, out, hfin);
  } else {
    gates_kernel<unsigned short><<<6144, 256, 0, stream>>>(x, WcT, bc, (unsigned short*)xg);
    const unsigned short* a0 = WhhT; const unsigned short* a1 = (const unsigned short*)xg;
    unsigned short* a2 = hbuf; unsigned short* a3 = rhb; int* a4 = flags;
    float* a5 = out; float* a6 = hfin;
    void* kargs[] = {&a0, &a1, &a2, &a3, &a4, &a5, &a6};
    hipError_t e = hipLaunchCooperativeKernel(
        reinterpret_cast<const void*>(&recur_kernel<unsigned short>),
        dim3(256), dim3(256), kargs, 0, stream);
    if (e != hipSuccess)
      recur_kernel<unsigned short><<<256, 256, 0, stream>>>(WhhT, (const unsigned short*)xg, hbuf, rhb, flags, out, hfin);
  }
}

// Round 2
// 4392.915 us; speedup vs baseline: 3.8265x; 3.8265x over previous
//
#include <hip/hip_runtime.h>
#include <stdint.h>

// ---------------------------------------------------------------------------
// CustomGRU: B=64, S=512, I=256, H=1024
//  xg = x @ (Wi@Wgx) + (bi@Wgx + bg)   (one fused GEMM, 3 gates concat, N=3072)
//  scan: z = sig(xz + h@Wzh); r = sig(xr + h@Wrh);
//        n = tanh(xn + (r*h)@Wnh);  h' = (1-z)n + z h      [(r*h)@W per py prec]
//
// R1: recurrence communication is fence-free — all cross-WG data (hbuf, rhbuf,
// flags) through relaxed AGENT-scope atomics (sc0 sc1 -> LLC-coherent, no
// buffer_wbl2). Weights register-resident (96 VGPR/lane), no LDS staging of h.
// ---------------------------------------------------------------------------

using f32x4  = __attribute__((ext_vector_type(4))) float;
using bf16x8 = __attribute__((ext_vector_type(8))) __bf16;
using u16x8  = __attribute__((ext_vector_type(8))) unsigned short;
using u16x4  = __attribute__((ext_vector_type(4))) unsigned short;
typedef unsigned long long ull;

__device__ __forceinline__ unsigned short f2bf(float x) {
  union { float f; uint32_t u; } v; v.f = x;
  uint32_t u = v.u;
  return (unsigned short)((u + 0x7fffu + ((u >> 16) & 1u)) >> 16);  // RNE
}
__device__ __forceinline__ float bf2f(unsigned short u) {
  union { uint32_t u; float f; } v; v.u = ((uint32_t)u) << 16;
  return v.f;
}
__device__ __forceinline__ bf16x8 ld_b8(const unsigned short* p) {
  return *(const bf16x8*)p;
}
__device__ __forceinline__ float xg_get(const float* p) { return *p; }
__device__ __forceinline__ float xg_get(const unsigned short* p) { return bf2f(*p); }
__device__ __forceinline__ void  xg_put(float* p, float v) { *p = v; }
__device__ __forceinline__ void  xg_put(unsigned short* p, float v) { *p = f2bf(v); }
__device__ __forceinline__ float sigm(float x) { return 1.f / (1.f + __expf(-x)); }
__device__ __forceinline__ float tanh_(float x) { float e = __expf(2.f * x); return 1.f - 2.f / (e + 1.f); }

__device__ __forceinline__ ull ld_agent(const ull* p) {
  return __hip_atomic_load(p, __ATOMIC_RELAXED, __HIP_MEMORY_SCOPE_AGENT);
}
__device__ __forceinline__ void st_agent(uint32_t* p, uint32_t v) {
  __hip_atomic_store(p, v, __ATOMIC_RELAXED, __HIP_MEMORY_SCOPE_AGENT);
}
__device__ __forceinline__ int ld_flag(const int* p) {
  return __hip_atomic_load(p, __ATOMIC_RELAXED, __HIP_MEMORY_SCOPE_AGENT);
}
__device__ __forceinline__ void st_flag(int* p, int v) {
  __hip_atomic_store(p, v, __ATOMIC_RELAXED, __HIP_MEMORY_SCOPE_AGENT);
}

// ---------------------------------------------------------------------------
// K1: WcT[n(3072)][i(256)] (bf16) = (Wi @ Wgx)^T.  1.6 GFLOP.
// ---------------------------------------------------------------------------
__global__ __launch_bounds__(256) void wc_kernel(
    const float* __restrict__ Wi, const float* __restrict__ Wz,
    const float* __restrict__ Wr, const float* __restrict__ Wn,
    unsigned short* __restrict__ WcT)
{
  const int ntile = blockIdx.x >> 4, itile = blockIdx.x & 15;  // 48 x 16
  const int n_g = ntile * 64 + (threadIdx.x & 63);             // 0..3071
  const int g = n_g >> 10, n = n_g & 1023;
  const float* Wg = (g == 0) ? Wz : (g == 1) ? Wr : Wn;        // rows [0,H) = W*_x
  const int i0 = itile * 16 + ((threadIdx.x >> 6) << 2);
  float a0 = 0.f, a1 = 0.f, a2 = 0.f, a3 = 0.f;
  for (int k = 0; k < 1024; ++k) {
    const float wv = Wg[(size_t)k * 1024 + n];
    a0 += Wi[(i0 + 0) * 1024 + k] * wv;
    a1 += Wi[(i0 + 1) * 1024 + k] * wv;
    a2 += Wi[(i0 + 2) * 1024 + k] * wv;
    a3 += Wi[(i0 + 3) * 1024 + k] * wv;
  }
  WcT[(size_t)n_g * 256 + i0 + 0] = f2bf(a0);
  WcT[(size_t)n_g * 256 + i0 + 1] = f2bf(a1);
  WcT[(size_t)n_g * 256 + i0 + 2] = f2bf(a2);
  WcT[(size_t)n_g * 256 + i0 + 3] = f2bf(a3);
}

// ---------------------------------------------------------------------------
// K2: bc[n(3072)] = bi @ Wgx + bg  (fp32)
// ---------------------------------------------------------------------------
__global__ __launch_bounds__(256) void bc_kernel(
    const float* __restrict__ bi, const float* __restrict__ Wz,
    const float* __restrict__ Wr, const float* __restrict__ Wn,
    const float* __restrict__ bz, const float* __restrict__ br,
    const float* __restrict__ bn, float* __restrict__ bc)
{
  const int n_g = blockIdx.x * 256 + threadIdx.x;
  const int g = n_g >> 10, n = n_g & 1023;
  const float* Wg = (g == 0) ? Wz : (g == 1) ? Wr : Wn;
  const float* bg = (g == 0) ? bz : (g == 1) ? br : bn;
  float acc = bg[n];
  for (int k = 0; k < 1024; ++k) acc += bi[k] * Wg[(size_t)k * 1024 + n];
  bc[n_g] = acc;
}

// ---------------------------------------------------------------------------
// K3: WhhT[g][col(1024)][k(1024)] (bf16) = Wg[H + k][col]  (tile transpose)
// ---------------------------------------------------------------------------
__global__ __launch_bounds__(256) void whT_kernel(
    const float* __restrict__ Wz, const float* __restrict__ Wr,
    const float* __restrict__ Wn, unsigned short* __restrict__ WhhT)
{
  __shared__ float tile[64][65];
  const int g = blockIdx.x >> 8;
  const int rem = blockIdx.x & 255;
  const int kt = rem >> 4, ct = rem & 15;
  const float* Wg = (g == 0) ? Wz : (g == 1) ? Wr : Wn;
  const int tx = threadIdx.x & 63, ty = threadIdx.x >> 6;
  #pragma unroll
  for (int j = 0; j < 16; ++j) {
    const int k = kt * 64 + ty + j * 4;
    tile[ty + j * 4][tx] = Wg[(size_t)(1024 + k) * 1024 + ct * 64 + tx];
  }
  __syncthreads();
  #pragma unroll
  for (int j = 0; j < 16; ++j) {
    const int c = ct * 64 + ty + j * 4;
    WhhT[((size_t)g * 1024 + c) * 1024 + kt * 64 + tx] = f2bf(tile[tx][ty + j * 4]);
  }
}

// ---------------------------------------------------------------------------
// K4: gates GEMM  xg[s][b][3072] = x @ Wc + bc.  M=32768, N=3072, K=256.
// ---------------------------------------------------------------------------
template <typename XT>
__global__ __launch_bounds__(256) void gates_kernel(
    const float* __restrict__ x, const unsigned short* __restrict__ WcT,
    const float* __restrict__ bc, XT* __restrict__ xg)
{
  __shared__ __align__(16) unsigned short As[128 * 72];
  __shared__ __align__(16) unsigned short Bs[128 * 72];
  const int t = threadIdx.x;
  const int lane = t & 63, wid = t >> 6;
  const int wm = wid >> 1, wn = wid & 1;
  const int ml = lane & 15, quad = lane >> 4;
  const int mb = blockIdx.x / 24, nb = blockIdx.x % 24;
  const int m0 = mb * 128, n0 = nb * 128;
  f32x4 acc[4][4];
  #pragma unroll
  for (int i = 0; i < 4; ++i)
    #pragma unroll
    for (int j = 0; j < 4; ++j) acc[i][j] = (f32x4){0.f, 0.f, 0.f, 0.f};

  for (int kc = 0; kc < 4; ++kc) {
    {
      const int row = t >> 4, c4 = t & 15;
      #pragma unroll
      for (int i = 0; i < 8; ++i) {
        const f32x4 v = *(const f32x4*)(x + (size_t)(m0 + row + i * 16) * 256 + kc * 64 + c4 * 4);
        u16x4 b4 = { f2bf(v[0]), f2bf(v[1]), f2bf(v[2]), f2bf(v[3]) };
        *(u16x4*)&As[(row + i * 16) * 72 + c4 * 4] = b4;
      }
      const int rowB = t >> 3, ch = t & 7;
      #pragma unroll
      for (int i = 0; i < 4; ++i) {
        const u16x8 v = *(const u16x8*)(WcT + (size_t)(n0 + rowB + i * 32) * 256 + kc * 64 + ch * 8);
        *(u16x8*)&Bs[(rowB + i * 32) * 72 + ch * 8] = v;
      }
    }
    __syncthreads();
    #pragma unroll
    for (int kt = 0; kt < 2; ++kt) {
      bf16x8 a[4], b[4];
      #pragma unroll
      for (int mt = 0; mt < 4; ++mt) a[mt] = ld_b8(&As[(wm * 64 + mt * 16 + ml) * 72 + kt * 32 + quad * 8]);
      #pragma unroll
      for (int nt = 0; nt < 4; ++nt) b[nt] = ld_b8(&Bs[(wn * 64 + nt * 16 + ml) * 72 + kt * 32 + quad * 8]);
      #pragma unroll
      for (int mt = 0; mt < 4; ++mt)
        #pragma unroll
        for (int nt = 0; nt < 4; ++nt)
          acc[mt][nt] = __builtin_amdgcn_mfma_f32_16x16x32_bf16(a[mt], b[nt], acc[mt][nt], 0, 0, 0);
    }
    __syncthreads();
  }
  #pragma unroll
  for (int nt = 0; nt < 4; ++nt) {
    const int n = n0 + wn * 64 + nt * 16 + ml;
    const float bcv = bc[n];
    #pragma unroll
    for (int mt = 0; mt < 4; ++mt) {
      #pragma unroll
      for (int r = 0; r < 4; ++r) {
        const int m = m0 + wm * 64 + mt * 16 + quad * 4 + r;
        const int b = m >> 9, s = m & 511;
        xg_put(&xg[((size_t)s * 64 + b) * 3072 + n], acc[mt][nt][r] + bcv);
      }
    }
  }
}

// ---------------------------------------------------------------------------
// K5: persistent recurrence. 256 WGs = 4 batch-groups(16 b) x 64 col-groups(16 h).
// Fence-free: all cross-WG data via relaxed agent-scope atomics (LLC-coherent).
// Weights in registers (96 VGPR/lane); no LDS staging of h.
// ---------------------------------------------------------------------------
template <typename XT>
__global__ __launch_bounds__(256, 1) void recur_kernel(
    const unsigned short* __restrict__ WhhT, const XT* __restrict__ xg,
    unsigned short* __restrict__ hbuf, unsigned short* __restrict__ rhbuf,
    int* __restrict__ flags, float* __restrict__ out, float* __restrict__ hfin)
{
  __shared__ __align__(16) float red[8 * 256];  // 8KB partial sums
  __shared__ float zbuf[256];
  __shared__ float hprev[256];  // exact fp32 h slice of this WG
  __shared__ float scr[256];    // pack scratch (rh / h-new)

  const int tid  = threadIdx.x;
  const int lane = tid & 63;
  const int wid  = tid >> 6;
  const int ml   = lane & 15;
  const int quad = lane >> 4;
  const int bg   = blockIdx.x & 3;   // batch group 0..3 (domain)
  const int ng   = blockIdx.x >> 2;  // col group 0..63

  // ---- weights -> registers: wave `wid` owns kt = wid*8 .. wid*8+7 ----
  bf16x8 wz_r[8], wr_r[8], wn_r[8];
  #pragma unroll
  for (int k8 = 0; k8 < 8; ++k8) {
    const int kt = wid * 8 + k8;
    const size_t base = (size_t)(ng * 16 + ml) * 1024 + kt * 32 + quad * 8;
    wz_r[k8] = ld_b8(WhhT + base);
    wr_r[k8] = ld_b8(WhhT + (1u << 20) + base);
    wn_r[k8] = ld_b8(WhhT + (2u << 20) + base);
  }
  hprev[tid] = 0.f;

  int* myflag = flags + (bg * 64 + ng) * 32;
  int* domf   = flags + (bg * 64 + lane) * 32;   // lane -> peer ng
  const ull*  hb_base = (const ull*)hbuf;        // [parity(16384)][b(256)][k]
  const ull*  rb_base = (const ull*)rhbuf;       // [b(256)][k]
  uint32_t*   hb_w    = (uint32_t*)hbuf;
  uint32_t*   rb_w    = (uint32_t*)rhbuf;
  __syncthreads();

  for (int t = 0; t < 512; ++t) {
    // ================= phase A: z, r =================
    // h fragments straight from LLC (sc1): row b = bg*16+ml, k = kt*32+quad*8
    bf16x8 hv[8];
    {
      const ull* hb = hb_base + (size_t)(t & 1) * 16384;
      #pragma unroll
      for (int k8 = 0; k8 < 8; ++k8) {
        const int kt = wid * 8 + k8;
        const size_t idx = (size_t)(bg * 16 + ml) * 256 + kt * 8 + quad * 2;
        union { ull q[2]; bf16x8 v; } u;
        u.q[0] = ld_agent(hb + idx);
        u.q[1] = ld_agent(hb + idx + 1);
        hv[k8] = u.v;
      }
    }
    float xgv[4];   // z (wid0) / r (wid1) pre-activations from xg
    float xgn[4];   // n pre-activations, prefetched for phase B (wid0)
    if (wid < 2) {
      const XT* xp = xg + ((size_t)t * 64 + bg * 16 + quad * 4) * 3072 + wid * 1024 + ng * 16 + ml;
      #pragma unroll
      for (int r = 0; r < 4; ++r) xgv[r] = xg_get(xp + (size_t)r * 3072);
    }
    if (wid == 0) {
      const XT* xp = xg + ((size_t)t * 64 + bg * 16 + quad * 4) * 3072 + 2048 + ng * 16 + ml;
      #pragma unroll
      for (int r = 0; r < 4; ++r) xgn[r] = xg_get(xp + (size_t)r * 3072);
    }

    f32x4 accZ = {0.f, 0.f, 0.f, 0.f}, accR = {0.f, 0.f, 0.f, 0.f};
    #pragma unroll
    for (int k8 = 0; k8 < 8; ++k8) {
      accZ = __builtin_amdgcn_mfma_f32_16x16x32_bf16(hv[k8], wz_r[k8], accZ, 0, 0, 0);
      accR = __builtin_amdgcn_mfma_f32_16x16x32_bf16(hv[k8], wr_r[k8], accR, 0, 0, 0);
    }
    *(f32x4*)&red[(wid * 2 + 0) * 256 + lane * 4] = accZ;
    *(f32x4*)&red[(wid * 2 + 1) * 256 + lane * 4] = accR;
    __syncthreads();

    if (wid == 0) {
      f32x4 s = {0.f, 0.f, 0.f, 0.f};
      #pragma unroll
      for (int w = 0; w < 4; ++w) s += *(const f32x4*)&red[(w * 2) * 256 + lane * 4];
      #pragma unroll
      for (int r = 0; r < 4; ++r) zbuf[(quad * 4 + r) * 16 + ml] = sigm(s[r] + xgv[r]);
    } else if (wid == 1) {
      f32x4 s = {0.f, 0.f, 0.f, 0.f};
      #pragma unroll
      for (int w = 0; w < 4; ++w) s += *(const f32x4*)&red[(w * 2 + 1) * 256 + lane * 4];
      #pragma unroll
      for (int r = 0; r < 4; ++r) {
        const int bl = quad * 4 + r;
        scr[bl * 16 + ml] = sigm(s[r] + xgv[r]) * hprev[bl * 16 + ml];
      }
    }
    __syncthreads();
    // pack rh (bf16 pairs) -> LLC
    if (tid < 128) {
      const int row = tid >> 3, pair = tid & 7;
      const uint32_t d = (uint32_t)f2bf(scr[row * 16 + pair * 2]) |
                         ((uint32_t)f2bf(scr[row * 16 + pair * 2 + 1]) << 16);
      st_agent(rb_w + (size_t)(bg * 16 + row) * 512 + ng * 8 + pair, d);
    }
    __syncthreads();  // drains vmcnt -> rh stores visible at LLC
    if (tid == 0) st_flag(myflag, 2 * t + 1);
    if (wid == 0) {
      const int target = 2 * t + 1;
      while (true) {
        const int v = ld_flag(domf + 0);  // lane's peer
        if (__all(v >= target)) break;
        __builtin_amdgcn_s_sleep(1);
      }
      __atomic_signal_fence(__ATOMIC_ACQUIRE);
    }
    __syncthreads();

    // ================= phase B: n, h' =================
    bf16x8 rv[8];
    #pragma unroll
    for (int k8 = 0; k8 < 8; ++k8) {
      const int kt = wid * 8 + k8;
      const size_t idx = (size_t)(bg * 16 + ml) * 256 + kt * 8 + quad * 2;
      union { ull q[2]; bf16x8 v; } u;
      u.q[0] = ld_agent(rb_base + idx);
      u.q[1] = ld_agent(rb_base + idx + 1);
      rv[k8] = u.v;
    }
    f32x4 accN = {0.f, 0.f, 0.f, 0.f};
    #pragma unroll
    for (int k8 = 0; k8 < 8; ++k8)
      accN = __builtin_amdgcn_mfma_f32_16x16x32_bf16(rv[k8], wn_r[k8], accN, 0, 0, 0);
    *(f32x4*)&red[wid * 256 + lane * 4] = accN;
    __syncthreads();

    if (wid == 0) {
      f32x4 s = {0.f, 0.f, 0.f, 0.f};
      #pragma unroll
      for (int w = 0; w < 4; ++w) s += *(const f32x4*)&red[w * 256 + lane * 4];
      #pragma unroll
      for (int r = 0; r < 4; ++r) {
        const int bl = quad * 4 + r;
        const float nv = tanh_(s[r] + xgn[r]);
        const float z  = zbuf[bl * 16 + ml];
        const float hv0 = hprev[bl * 16 + ml];
        const float hn = (1.f - z) * nv + z * hv0;
        hprev[bl * 16 + ml] = hn;
        scr[bl * 16 + ml]   = hn;
        const int b = bg * 16 + bl;
        __builtin_nontemporal_store(hn, &out[((size_t)b * 512 + t) * 1024 + ng * 16 + ml]);
        if (t == 511)
          __builtin_nontemporal_store(hn, &hfin[(size_t)b * 1024 + ng * 16 + ml]);
      }
    }
    __syncthreads();
    if (tid < 128) {
      const int row = tid >> 3, pair = tid & 7;
      const uint32_t d = (uint32_t)f2bf(scr[row * 16 + pair * 2]) |
                         ((uint32_t)f2bf(scr[row * 16 + pair * 2 + 1]) << 16);
      st_agent(hb_w + (size_t)((t + 1) & 1) * 32768 +
               (size_t)(bg * 16 + row) * 512 + ng * 8 + pair, d);
    }
    __syncthreads();  // drains vmcnt -> h stores visible at LLC
    if (tid == 0) st_flag(myflag, 2 * t + 2);
    if (wid == 0) {
      const int target = 2 * t + 2;
      while (true) {
        const int v = ld_flag(domf + 0);
        if (__all(v >= target)) break;
        __builtin_amdgcn_s_sleep(1);
      }
      __atomic_signal_fence(__ATOMIC_ACQUIRE);
    }
    __syncthreads();
  }
}

// ---------------------------------------------------------------------------
extern "C" void kernel_launch(void* const* d_in, const int* in_sizes, int n_in,
                              void* d_out, int out_size, void* d_ws, size_t ws_size,
                              hipStream_t stream)
{
  const float* x  = (const float*)d_in[0];
  const float* Wi = (const float*)d_in[1];
  const float* bi = (const float*)d_in[2];
  const float* Wz = (const float*)d_in[3];
  const float* bz = (const float*)d_in[4];
  const float* Wr = (const float*)d_in[5];
  const float* br = (const float*)d_in[6];
  const float* Wn = (const float*)d_in[7];
  const float* bn = (const float*)d_in[8];
  float* out  = (float*)d_out;
  float* hfin = out + (size_t)64 * 512 * 1024;

  char* ws = (char*)d_ws;
  size_t off = 0;
  auto take = [&](size_t b) { size_t o = off; off += (b + 255) & ~(size_t)255; return o; };
  unsigned short* WhhT = (unsigned short*)(ws + take((size_t)3 * 1024 * 1024 * 2));
  unsigned short* WcT  = (unsigned short*)(ws + take((size_t)3072 * 256 * 2));
  float*          bc   = (float*)(ws + take(3072 * 4));
  unsigned short* hbuf = (unsigned short*)(ws + take((size_t)2 * 64 * 1024 * 2));
  unsigned short* rhb  = (unsigned short*)(ws + take((size_t)64 * 1024 * 2));
  int*            flags = (int*)(ws + take(256 * 32 * 4));
  const size_t xg_off = off;
  const bool xg_f32 = (ws_size >= xg_off + (size_t)32768 * 3072 * 4);
  void* xg = (void*)(ws + xg_off);

  hipMemsetAsync(hbuf, 0, (size_t)2 * 64 * 1024 * 2, stream);
  hipMemsetAsync(flags, 0, 256 * 32 * 4, stream);

  wc_kernel<<<768, 256, 0, stream>>>(Wi, Wz, Wr, Wn, WcT);
  bc_kernel<<<12, 256, 0, stream>>>(bi, Wz, Wr, Wn, bz, br, bn, bc);
  whT_kernel<<<768, 256, 0, stream>>>(Wz, Wr, Wn, WhhT);

  if (xg_f32) {
    gates_kernel<float><<<6144, 256, 0, stream>>>(x, WcT, bc, (float*)xg);
    const unsigned short* a0 = WhhT; const float* a1 = (const float*)xg;
    unsigned short* a2 = hbuf; unsigned short* a3 = rhb; int* a4 = flags;
    float* a5 = out; float* a6 = hfin;
    void* kargs[] = {&a0, &a1, &a2, &a3, &a4, &a5, &a6};
    hipError_t e = hipLaunchCooperativeKernel(
        reinterpret_cast<const void*>(&recur_kernel<float>),
        dim3(256), dim3(256), kargs, 0, stream);
    if (e != hipSuccess)
      recur_kernel<float><<<256, 256, 0, stream>>>(WhhT, (const float*)xg, hbuf, rhb, flags, out, hfin);
  } else {
    gates_kernel<unsigned short><<<6144, 256, 0, stream>>>(x, WcT, bc, (unsigned short*)xg);
    const unsigned short* a0 = WhhT; const unsigned short* a1 = (const unsigned short*)xg;
    unsigned short* a2 = hbuf; unsigned short* a3 = rhb; int* a4 = flags;
    float* a5 = out; float* a6 = hfin;
    void* kargs[] = {&a0, &a1, &a2, &a3, &a4, &a5, &a6};
    hipError_t e = hipLaunchCooperativeKernel(
        reinterpret_cast<const void*>(&recur_kernel<unsigned short>),
        dim3(256), dim3(256), kargs, 0, stream);
    if (e != hipSuccess)
      recur_kernel<unsigned short><<<256, 256, 0, stream>>>(WhhT, (const unsigned short*)xg, hbuf, rhb, flags, out, hfin);
  }
}